// Round 1
// baseline (14915.779 us; speedup 1.0000x reference)
//
#include <hip/hip_runtime.h>
#include <math.h>

#define BB   2
#define CIN  32
#define CC   64
#define HH   352
#define WW   1216
#define HO   176
#define WOUT 608
#define HWO  (HO*WOUT)
#define NS   10000
#define KNN  7
#define HID  65

// ---------------- stride-2 3x3 conv, two weight sets over one input ----------
// out0 = relu(conv(x,w0)+b0), out1 = conv(x,w1)+b1
__global__ __launch_bounds__(64) void conv_s2_dual(
    const float* __restrict__ x,
    const float* __restrict__ w0, const float* __restrict__ b0,
    const float* __restrict__ w1, const float* __restrict__ b1,
    float* __restrict__ out0, float* __restrict__ out1)
{
    int wo = blockIdx.x * 64 + threadIdx.x;
    if (wo >= WOUT) return;
    int ho = blockIdx.y;
    int bc = blockIdx.z;           // b*CC + co
    int b  = bc >> 6, co = bc & 63;

    float acc0 = b0[co], acc1 = b1[co];
    int hi0 = ho*2 - 1, wi0 = wo*2 - 1;

    for (int cin = 0; cin < CIN; ++cin) {
        const float* xp  = x  + ((size_t)(b*CIN + cin) * HH) * WW;
        const float* wp0 = w0 + (co*CIN + cin) * 9;
        const float* wp1 = w1 + (co*CIN + cin) * 9;
        #pragma unroll
        for (int kh = 0; kh < 3; ++kh) {
            int hi = hi0 + kh;
            if ((unsigned)hi >= HH) continue;
            const float* xr = xp + (size_t)hi * WW;
            #pragma unroll
            for (int kw = 0; kw < 3; ++kw) {
                int wi = wi0 + kw;
                if ((unsigned)wi >= WW) continue;
                float v = xr[wi];
                acc0 = fmaf(v, wp0[kh*3+kw], acc0);
                acc1 = fmaf(v, wp1[kh*3+kw], acc1);
            }
        }
    }
    size_t o = ((size_t)bc * HO + ho) * WOUT + wo;
    out0[o] = fmaxf(acc0, 0.f);
    out1[o] = acc1;
}

// ---------------- stride-1 3x3 conv (64->64) + residual(d1) + relu ----------
// io holds d1 on entry; result written back in place (same element).
__global__ __launch_bounds__(64) void conv_s1_add_relu(
    const float* __restrict__ x,
    const float* __restrict__ w, const float* __restrict__ bias,
    float* __restrict__ io)
{
    int wo = blockIdx.x * 64 + threadIdx.x;
    if (wo >= WOUT) return;
    int ho = blockIdx.y;
    int bc = blockIdx.z;
    int b  = bc >> 6, co = bc & 63;

    float acc = bias[co];
    int hi0 = ho - 1, wi0 = wo - 1;

    for (int cin = 0; cin < CC; ++cin) {
        const float* xp = x + ((size_t)(b*CC + cin) * HO) * WOUT;
        const float* wp = w + (co*CC + cin) * 9;
        #pragma unroll
        for (int kh = 0; kh < 3; ++kh) {
            int hi = hi0 + kh;
            if ((unsigned)hi >= HO) continue;
            const float* xr = xp + (size_t)hi * WOUT;
            #pragma unroll
            for (int kw = 0; kw < 3; ++kw) {
                int wi = wi0 + kw;
                if ((unsigned)wi >= WOUT) continue;
                acc = fmaf(xr[wi], wp[kh*3+kw], acc);
            }
        }
    }
    size_t o = ((size_t)bc * HO + ho) * WOUT + wo;
    io[o] = fmaxf(acc + io[o], 0.f);
}

// ---------------- compact the NS sampled pixels into [b][n][c] --------------
__global__ __launch_bounds__(64) void samp_gather(
    const float* __restrict__ f0, const float* __restrict__ g0,
    const int* __restrict__ sidxs,
    float* __restrict__ fs, float* __restrict__ gs)
{
    int n = blockIdx.x, b = blockIdx.y, lane = threadIdx.x;
    int p = sidxs[b*NS + n];
    fs[((size_t)(b*NS + n))*CC + lane] = f0[((size_t)(b*CC + lane))*HWO + p];
    gs[((size_t)(b*NS + n))*CC + lane] = g0[((size_t)(b*CC + lane))*HWO + p];
}

// ---------------- last-occurrence-wins resolution of duplicate sidxs --------
__global__ void win_kernel(const int* __restrict__ sidxs, int* __restrict__ win)
{
    int i = blockIdx.x * blockDim.x + threadIdx.x;
    if (i >= BB*NS) return;
    int b = i / NS, n = i - b*NS;
    atomicMax(&win[b*HWO + sidxs[i]], n);   // win pre-set to -1
}

// ---------------- KNN attention MLP + softmax + aggregation -----------------
// one wave per (b,n); lane = hidden unit h (h=64 computed redundantly uniform)
__global__ __launch_bounds__(64) void attn_kernel(
    const float* __restrict__ dsamp, const float* __restrict__ rsamp,
    const float* __restrict__ spoints, const int* __restrict__ nnidxs,
    const float* __restrict__ dw1, const float* __restrict__ db1,
    const float* __restrict__ dw2, const float* __restrict__ db2,
    const float* __restrict__ rw1, const float* __restrict__ rb1,
    const float* __restrict__ rw2, const float* __restrict__ rb2,
    const float* __restrict__ d_bias, const float* __restrict__ r_bias,
    float* __restrict__ aggD, float* __restrict__ aggR)
{
    int n = blockIdx.x, b = blockIdx.y, lane = threadIdx.x;

    __shared__ float ds[CC], rs[CC];
    __shared__ float dnn[KNN][CC], rnn[KNN][CC];
    __shared__ float ps[4], nnp[KNN][4];
    __shared__ float scd[KNN], scr[KNN];

    ds[lane] = dsamp[((size_t)(b*NS + n))*CC + lane];
    rs[lane] = rsamp[((size_t)(b*NS + n))*CC + lane];
    if (lane < 3) ps[lane] = spoints[(b*3 + lane)*NS + n];

    for (int k = 0; k < KNN; ++k) {
        int m = nnidxs[((size_t)(b*NS + n))*KNN + k];
        dnn[k][lane] = dsamp[((size_t)(b*NS + m))*CC + lane];
        rnn[k][lane] = rsamp[((size_t)(b*NS + m))*CC + lane];
        if (lane < 3) nnp[k][lane] = spoints[(b*3 + lane)*NS + m];
    }
    __syncthreads();

    for (int k = 0; k < KNN; ++k) {
        float hd   = db1[lane], hr   = rb1[lane];
        float hd64 = db1[64],   hr64 = rb1[64];
        for (int j = 0; j < CC; ++j) {
            float f = dnn[k][j] - ds[j];
            hd   = fmaf(f, dw1[j*HID + lane], hd);
            hr   = fmaf(f, rw1[j*HID + lane], hr);
            hd64 = fmaf(f, dw1[j*HID + 64],   hd64);
            hr64 = fmaf(f, rw1[j*HID + 64],   hr64);
        }
        for (int j = 0; j < CC; ++j) {
            float f = rnn[k][j] - rs[j];
            hd   = fmaf(f, dw1[(CC + j)*HID + lane], hd);
            hr   = fmaf(f, rw1[(CC + j)*HID + lane], hr);
            hd64 = fmaf(f, dw1[(CC + j)*HID + 64],   hd64);
            hr64 = fmaf(f, rw1[(CC + j)*HID + 64],   hr64);
        }
        #pragma unroll
        for (int j = 0; j < 3; ++j) {
            float f = nnp[k][j] - ps[j];
            hd   = fmaf(f, dw1[(2*CC + j)*HID + lane], hd);
            hr   = fmaf(f, rw1[(2*CC + j)*HID + lane], hr);
            hd64 = fmaf(f, dw1[(2*CC + j)*HID + 64],   hd64);
            hr64 = fmaf(f, rw1[(2*CC + j)*HID + 64],   hr64);
        }
        // leaky_relu(0.2)
        hd   = hd   > 0.f ? hd   : 0.2f*hd;
        hr   = hr   > 0.f ? hr   : 0.2f*hr;
        hd64 = hd64 > 0.f ? hd64 : 0.2f*hd64;
        hr64 = hr64 > 0.f ? hr64 : 0.2f*hr64;

        float pd = hd * dw2[lane];
        float pr = hr * rw2[lane];
        #pragma unroll
        for (int off = 32; off; off >>= 1) {
            pd += __shfl_xor(pd, off);
            pr += __shfl_xor(pr, off);
        }
        if (lane == 0) {
            scd[k] = pd + hd64*dw2[64] + db2[0];
            scr[k] = pr + hr64*rw2[64] + rb2[0];
        }
    }
    __syncthreads();

    // softmax over KNN (redundant per lane), then aggregate
    float mxd = -1e30f, mxr = -1e30f;
    #pragma unroll
    for (int k = 0; k < KNN; ++k) { mxd = fmaxf(mxd, scd[k]); mxr = fmaxf(mxr, scr[k]); }
    float ed[KNN], er[KNN], sd = 0.f, sr = 0.f;
    #pragma unroll
    for (int k = 0; k < KNN; ++k) {
        ed[k] = expf(scd[k] - mxd); sd += ed[k];
        er[k] = expf(scr[k] - mxr); sr += er[k];
    }
    float isd = 1.f/sd, isr = 1.f/sr;
    float accd = d_bias[lane], accr = r_bias[lane];
    #pragma unroll
    for (int k = 0; k < KNN; ++k) {
        accd = fmaf(ed[k]*isd, dnn[k][lane], accd);
        accr = fmaf(er[k]*isr, rnn[k][lane], accr);
    }
    aggD[((size_t)(b*NS + n))*CC + lane] = accd;
    aggR[((size_t)(b*NS + n))*CC + lane] = accr;
}

// ---------------- mask blend + scatter winner, in place ---------------------
__global__ void blend_kernel(float* __restrict__ f0,
    const int* __restrict__ masks, const int* __restrict__ win,
    const float* __restrict__ agg)
{
    int i = blockIdx.x * blockDim.x + threadIdx.x;
    if (i >= BB*CC*HWO) return;
    int b   = i / (CC*HWO);
    int rem = i - b*(CC*HWO);
    int c   = rem / HWO;
    int p   = rem - c*HWO;
    float m = (float)masks[b*HWO + p];
    float v = (1.f - m) * f0[i];
    int wn = win[b*HWO + p];
    if (wn >= 0) v += agg[((size_t)(b*NS + wn))*CC + c];
    f0[i] = v;
}

extern "C" void kernel_launch(void* const* d_in, const int* in_sizes, int n_in,
                              void* d_out, int out_size, void* d_ws, size_t ws_size,
                              hipStream_t stream)
{
    const float* d_feat  = (const float*)d_in[0];
    const float* r_feat  = (const float*)d_in[1];
    const float* spoints = (const float*)d_in[2];
    const int*   masks   = (const int*)d_in[3];
    const float* d_c0w = (const float*)d_in[4];
    const float* d_c0b = (const float*)d_in[5];
    const float* d_c1w = (const float*)d_in[6];
    const float* d_c1b = (const float*)d_in[7];
    const float* d_c2w = (const float*)d_in[8];
    const float* d_c2b = (const float*)d_in[9];
    const float* r_c0w = (const float*)d_in[10];
    const float* r_c0b = (const float*)d_in[11];
    const float* r_c1w = (const float*)d_in[12];
    const float* r_c1b = (const float*)d_in[13];
    const float* r_c2w = (const float*)d_in[14];
    const float* r_c2b = (const float*)d_in[15];
    const float* dw1 = (const float*)d_in[16];
    const float* db1 = (const float*)d_in[17];
    const float* dw2 = (const float*)d_in[18];
    const float* db2 = (const float*)d_in[19];
    const float* rw1 = (const float*)d_in[20];
    const float* rb1 = (const float*)d_in[21];
    const float* rw2 = (const float*)d_in[22];
    const float* rb2 = (const float*)d_in[23];
    const float* d_bias = (const float*)d_in[24];
    const float* r_bias = (const float*)d_in[25];
    const int* sidxs  = (const int*)d_in[26];
    const int* nnidxs = (const int*)d_in[27];

    float* out   = (float*)d_out;
    float* d1buf = out;                                 // [B,C,HO,WO]
    float* r1buf = out + (size_t)BB*CC*HWO;

    float* ws = (float*)d_ws;
    size_t off = 0;
    float* d0    = ws + off; off += (size_t)BB*CC*HWO;  // 54.8 MB
    float* r0    = ws + off; off += (size_t)BB*CC*HWO;  // 54.8 MB
    float* aggD  = ws + off; off += (size_t)BB*NS*CC;   // 5.1 MB
    float* aggR  = ws + off; off += (size_t)BB*NS*CC;
    float* dsamp = ws + off; off += (size_t)BB*NS*CC;
    float* rsamp = ws + off; off += (size_t)BB*NS*CC;
    int*   win   = (int*)(ws + off);                    // B*HWO ints

    dim3 cgrid((WOUT + 63)/64, HO, BB*CC);

    conv_s2_dual<<<cgrid, 64, 0, stream>>>(d_feat, d_c0w, d_c0b, d_c1w, d_c1b, d0, d1buf);
    conv_s2_dual<<<cgrid, 64, 0, stream>>>(r_feat, r_c0w, r_c0b, r_c1w, r_c1b, r0, r1buf);

    hipMemsetAsync(win, 0xFF, (size_t)BB*HWO*sizeof(int), stream);
    win_kernel<<<(BB*NS + 255)/256, 256, 0, stream>>>(sidxs, win);

    samp_gather<<<dim3(NS, BB), 64, 0, stream>>>(d0, r0, sidxs, dsamp, rsamp);

    attn_kernel<<<dim3(NS, BB), 64, 0, stream>>>(dsamp, rsamp, spoints, nnidxs,
        dw1, db1, dw2, db2, rw1, rb1, rw2, rb2, d_bias, r_bias, aggD, aggR);

    int nelem = BB*CC*HWO;
    blend_kernel<<<(nelem + 255)/256, 256, 0, stream>>>(d0, masks, win, aggD);
    blend_kernel<<<(nelem + 255)/256, 256, 0, stream>>>(r0, masks, win, aggR);

    conv_s1_add_relu<<<cgrid, 64, 0, stream>>>(d0, d_c2w, d_c2b, d1buf);
    conv_s1_add_relu<<<cgrid, 64, 0, stream>>>(r0, r_c2w, r_c2b, r1buf);
}

// Round 2
// 2303.487 us; speedup vs baseline: 6.4753x; 6.4753x over previous
//
#include <hip/hip_runtime.h>
#include <math.h>

#define BB   2
#define CIN  32
#define CC   64
#define HH   352
#define WW   1216
#define HO   176
#define WOUT 608
#define HWO  (HO*WOUT)
#define NS   10000
#define KNN  7
#define HID  65

#define TW 32
#define TH 4

// ============ stride-1 3x3 conv (64->64), all 64 co per block, + residual ====
// io holds d1 on entry; result written back in place.
__global__ __launch_bounds__(256) void conv_s1_tiled(
    const float* __restrict__ x, const float* __restrict__ w,
    const float* __restrict__ bias, float* __restrict__ io)
{
    __shared__ float sin_[8][TH+2][TW+2];   // 8*6*34 = 6.5 KB
    __shared__ float sw[8][9][CC];          // 18.4 KB

    int tid = threadIdx.x;
    int tx = tid & 31, tg = tid >> 5;       // tg in 0..7
    int x0 = blockIdx.x * TW, h0 = blockIdx.y * TH, b = blockIdx.z;
    int cobase = tg * 8;

    float acc[TH][8];
    #pragma unroll
    for (int c = 0; c < 8; ++c) {
        float bv = bias[cobase + c];
        #pragma unroll
        for (int r = 0; r < TH; ++r) acc[r][c] = bv;
    }

    for (int cc = 0; cc < CC; cc += 8) {
        // stage input tile: rows h0-1..h0+4, cols x0-1..x0+32
        for (int idx = tid; idx < 8*6*34; idx += 256) {
            int cin = idx / (6*34); int rem = idx - cin*(6*34);
            int row = rem / 34;     int col = rem - row*34;
            int hi = h0 - 1 + row, wi = x0 - 1 + col;
            float v = 0.f;
            if ((unsigned)hi < HO && (unsigned)wi < WOUT)
                v = x[((size_t)(b*CC + cc + cin)*HO + hi)*WOUT + wi];
            sin_[cin][row][col] = v;
        }
        // stage weights as [cin][tap][co]
        for (int idx = tid; idx < 8*9*CC; idx += 256) {
            int co = idx & 63; int t = idx >> 6;   // t = cin*9+tap
            int cin = t / 9, tap = t - cin*9;
            sw[cin][tap][co] = w[((size_t)co*CC + cc + cin)*9 + tap];
        }
        __syncthreads();

        for (int cin = 0; cin < 8; ++cin) {
            #pragma unroll
            for (int kh = 0; kh < 3; ++kh) {
                #pragma unroll
                for (int kw = 0; kw < 3; ++kw) {
                    int tap = kh*3 + kw;
                    float wv[8];
                    *(float4*)&wv[0] = *(const float4*)&sw[cin][tap][cobase];
                    *(float4*)&wv[4] = *(const float4*)&sw[cin][tap][cobase+4];
                    float iv[TH];
                    #pragma unroll
                    for (int r = 0; r < TH; ++r) iv[r] = sin_[cin][r+kh][tx+kw];
                    #pragma unroll
                    for (int r = 0; r < TH; ++r)
                        #pragma unroll
                        for (int c = 0; c < 8; ++c)
                            acc[r][c] = fmaf(iv[r], wv[c], acc[r][c]);
                }
            }
        }
        __syncthreads();
    }

    #pragma unroll
    for (int c = 0; c < 8; ++c)
        #pragma unroll
        for (int r = 0; r < TH; ++r) {
            size_t o = ((size_t)(b*CC + cobase + c)*HO + h0 + r)*WOUT + x0 + tx;
            io[o] = fmaxf(acc[r][c] + io[o], 0.f);
        }
}

// ============ stride-2 3x3 conv (32->64), dual weight sets, all co per block =
// out0 = relu(conv(x,w0)+b0), out1 = conv(x,w1)+b1
__global__ __launch_bounds__(256) void conv_s2_dual_tiled(
    const float* __restrict__ x,
    const float* __restrict__ w0, const float* __restrict__ b0,
    const float* __restrict__ w1, const float* __restrict__ b1,
    float* __restrict__ out0, float* __restrict__ out1)
{
    __shared__ float sin_[8][9][66];        // 19 KB
    __shared__ float sw0[8][9][CC];         // 18.4 KB
    __shared__ float sw1[8][9][CC];         // 18.4 KB

    int tid = threadIdx.x;
    int tx = tid & 31, tg = tid >> 5;
    int x0 = blockIdx.x * TW, h0 = blockIdx.y * TH, b = blockIdx.z;
    int cobase = tg * 8;

    float acc0[TH][8], acc1[TH][8];
    #pragma unroll
    for (int c = 0; c < 8; ++c) {
        float bv0 = b0[cobase + c], bv1 = b1[cobase + c];
        #pragma unroll
        for (int r = 0; r < TH; ++r) { acc0[r][c] = bv0; acc1[r][c] = bv1; }
    }

    for (int cc = 0; cc < CIN; cc += 8) {
        // stage input: rows 2h0-1..2h0+7 (9), cols 2x0-1..2x0+64 (66)
        for (int idx = tid; idx < 8*9*66; idx += 256) {
            int cin = idx / (9*66); int rem = idx - cin*(9*66);
            int row = rem / 66;     int col = rem - row*66;
            int hi = 2*h0 - 1 + row, wi = 2*x0 - 1 + col;
            float v = 0.f;
            if ((unsigned)hi < HH && (unsigned)wi < WW)
                v = x[((size_t)(b*CIN + cc + cin)*HH + hi)*WW + wi];
            sin_[cin][row][col] = v;
        }
        for (int idx = tid; idx < 8*9*CC; idx += 256) {
            int co = idx & 63; int t = idx >> 6;
            int cin = t / 9, tap = t - cin*9;
            size_t g = ((size_t)co*CIN + cc + cin)*9 + tap;
            sw0[cin][tap][co] = w0[g];
            sw1[cin][tap][co] = w1[g];
        }
        __syncthreads();

        for (int cin = 0; cin < 8; ++cin) {
            #pragma unroll
            for (int kh = 0; kh < 3; ++kh) {
                #pragma unroll
                for (int kw = 0; kw < 3; ++kw) {
                    int tap = kh*3 + kw;
                    float wv0[8], wv1[8];
                    *(float4*)&wv0[0] = *(const float4*)&sw0[cin][tap][cobase];
                    *(float4*)&wv0[4] = *(const float4*)&sw0[cin][tap][cobase+4];
                    *(float4*)&wv1[0] = *(const float4*)&sw1[cin][tap][cobase];
                    *(float4*)&wv1[4] = *(const float4*)&sw1[cin][tap][cobase+4];
                    float iv[TH];
                    #pragma unroll
                    for (int r = 0; r < TH; ++r) iv[r] = sin_[cin][2*r+kh][2*tx+kw];
                    #pragma unroll
                    for (int r = 0; r < TH; ++r)
                        #pragma unroll
                        for (int c = 0; c < 8; ++c) {
                            acc0[r][c] = fmaf(iv[r], wv0[c], acc0[r][c]);
                            acc1[r][c] = fmaf(iv[r], wv1[c], acc1[r][c]);
                        }
                }
            }
        }
        __syncthreads();
    }

    #pragma unroll
    for (int c = 0; c < 8; ++c)
        #pragma unroll
        for (int r = 0; r < TH; ++r) {
            size_t o = ((size_t)(b*CC + cobase + c)*HO + h0 + r)*WOUT + x0 + tx;
            out0[o] = fmaxf(acc0[r][c], 0.f);
            out1[o] = acc1[r][c];
        }
}

// ---------------- compact the NS sampled pixels into [b][n][c] --------------
__global__ __launch_bounds__(64) void samp_gather(
    const float* __restrict__ f0, const float* __restrict__ g0,
    const int* __restrict__ sidxs,
    float* __restrict__ fs, float* __restrict__ gs)
{
    int n = blockIdx.x, b = blockIdx.y, lane = threadIdx.x;
    int p = sidxs[b*NS + n];
    fs[((size_t)(b*NS + n))*CC + lane] = f0[((size_t)(b*CC + lane))*HWO + p];
    gs[((size_t)(b*NS + n))*CC + lane] = g0[((size_t)(b*CC + lane))*HWO + p];
}

// ---------------- last-occurrence-wins resolution of duplicate sidxs --------
__global__ void win_kernel(const int* __restrict__ sidxs, int* __restrict__ win)
{
    int i = blockIdx.x * blockDim.x + threadIdx.x;
    if (i >= BB*NS) return;
    int b = i / NS, n = i - b*NS;
    atomicMax(&win[b*HWO + sidxs[i]], n);   // win pre-set to -1
}

// ---------------- KNN attention MLP + softmax + aggregation -----------------
__global__ __launch_bounds__(64) void attn_kernel(
    const float* __restrict__ dsamp, const float* __restrict__ rsamp,
    const float* __restrict__ spoints, const int* __restrict__ nnidxs,
    const float* __restrict__ dw1, const float* __restrict__ db1,
    const float* __restrict__ dw2, const float* __restrict__ db2,
    const float* __restrict__ rw1, const float* __restrict__ rb1,
    const float* __restrict__ rw2, const float* __restrict__ rb2,
    const float* __restrict__ d_bias, const float* __restrict__ r_bias,
    float* __restrict__ aggD, float* __restrict__ aggR)
{
    int n = blockIdx.x, b = blockIdx.y, lane = threadIdx.x;

    __shared__ float ds[CC], rs[CC];
    __shared__ float dnn[KNN][CC], rnn[KNN][CC];
    __shared__ float ps[4], nnp[KNN][4];
    __shared__ float scd[KNN], scr[KNN];

    ds[lane] = dsamp[((size_t)(b*NS + n))*CC + lane];
    rs[lane] = rsamp[((size_t)(b*NS + n))*CC + lane];
    if (lane < 3) ps[lane] = spoints[(b*3 + lane)*NS + n];

    for (int k = 0; k < KNN; ++k) {
        int m = nnidxs[((size_t)(b*NS + n))*KNN + k];
        dnn[k][lane] = dsamp[((size_t)(b*NS + m))*CC + lane];
        rnn[k][lane] = rsamp[((size_t)(b*NS + m))*CC + lane];
        if (lane < 3) nnp[k][lane] = spoints[(b*3 + lane)*NS + m];
    }
    __syncthreads();

    for (int k = 0; k < KNN; ++k) {
        float hd   = db1[lane], hr   = rb1[lane];
        float hd64 = db1[64],   hr64 = rb1[64];
        for (int j = 0; j < CC; ++j) {
            float f = dnn[k][j] - ds[j];
            hd   = fmaf(f, dw1[j*HID + lane], hd);
            hr   = fmaf(f, rw1[j*HID + lane], hr);
            hd64 = fmaf(f, dw1[j*HID + 64],   hd64);
            hr64 = fmaf(f, rw1[j*HID + 64],   hr64);
        }
        for (int j = 0; j < CC; ++j) {
            float f = rnn[k][j] - rs[j];
            hd   = fmaf(f, dw1[(CC + j)*HID + lane], hd);
            hr   = fmaf(f, rw1[(CC + j)*HID + lane], hr);
            hd64 = fmaf(f, dw1[(CC + j)*HID + 64],   hd64);
            hr64 = fmaf(f, rw1[(CC + j)*HID + 64],   hr64);
        }
        #pragma unroll
        for (int j = 0; j < 3; ++j) {
            float f = nnp[k][j] - ps[j];
            hd   = fmaf(f, dw1[(2*CC + j)*HID + lane], hd);
            hr   = fmaf(f, rw1[(2*CC + j)*HID + lane], hr);
            hd64 = fmaf(f, dw1[(2*CC + j)*HID + 64],   hd64);
            hr64 = fmaf(f, rw1[(2*CC + j)*HID + 64],   hr64);
        }
        hd   = hd   > 0.f ? hd   : 0.2f*hd;
        hr   = hr   > 0.f ? hr   : 0.2f*hr;
        hd64 = hd64 > 0.f ? hd64 : 0.2f*hd64;
        hr64 = hr64 > 0.f ? hr64 : 0.2f*hr64;

        float pd = hd * dw2[lane];
        float pr = hr * rw2[lane];
        #pragma unroll
        for (int off = 32; off; off >>= 1) {
            pd += __shfl_xor(pd, off);
            pr += __shfl_xor(pr, off);
        }
        if (lane == 0) {
            scd[k] = pd + hd64*dw2[64] + db2[0];
            scr[k] = pr + hr64*rw2[64] + rb2[0];
        }
    }
    __syncthreads();

    float mxd = -1e30f, mxr = -1e30f;
    #pragma unroll
    for (int k = 0; k < KNN; ++k) { mxd = fmaxf(mxd, scd[k]); mxr = fmaxf(mxr, scr[k]); }
    float ed[KNN], er[KNN], sd = 0.f, sr = 0.f;
    #pragma unroll
    for (int k = 0; k < KNN; ++k) {
        ed[k] = expf(scd[k] - mxd); sd += ed[k];
        er[k] = expf(scr[k] - mxr); sr += er[k];
    }
    float isd = 1.f/sd, isr = 1.f/sr;
    float accd = d_bias[lane], accr = r_bias[lane];
    #pragma unroll
    for (int k = 0; k < KNN; ++k) {
        accd = fmaf(ed[k]*isd, dnn[k][lane], accd);
        accr = fmaf(er[k]*isr, rnn[k][lane], accr);
    }
    aggD[((size_t)(b*NS + n))*CC + lane] = accd;
    aggR[((size_t)(b*NS + n))*CC + lane] = accr;
}

// ---------------- mask blend + scatter winner, in place ---------------------
__global__ void blend_kernel(float* __restrict__ f0,
    const int* __restrict__ masks, const int* __restrict__ win,
    const float* __restrict__ agg)
{
    int i = blockIdx.x * blockDim.x + threadIdx.x;
    if (i >= BB*CC*HWO) return;
    int b   = i / (CC*HWO);
    int rem = i - b*(CC*HWO);
    int c   = rem / HWO;
    int p   = rem - c*HWO;
    float m = (float)masks[b*HWO + p];
    float v = (1.f - m) * f0[i];
    int wn = win[b*HWO + p];
    if (wn >= 0) v += agg[((size_t)(b*NS + wn))*CC + c];
    f0[i] = v;
}

extern "C" void kernel_launch(void* const* d_in, const int* in_sizes, int n_in,
                              void* d_out, int out_size, void* d_ws, size_t ws_size,
                              hipStream_t stream)
{
    const float* d_feat  = (const float*)d_in[0];
    const float* r_feat  = (const float*)d_in[1];
    const float* spoints = (const float*)d_in[2];
    const int*   masks   = (const int*)d_in[3];
    const float* d_c0w = (const float*)d_in[4];
    const float* d_c0b = (const float*)d_in[5];
    const float* d_c1w = (const float*)d_in[6];
    const float* d_c1b = (const float*)d_in[7];
    const float* d_c2w = (const float*)d_in[8];
    const float* d_c2b = (const float*)d_in[9];
    const float* r_c0w = (const float*)d_in[10];
    const float* r_c0b = (const float*)d_in[11];
    const float* r_c1w = (const float*)d_in[12];
    const float* r_c1b = (const float*)d_in[13];
    const float* r_c2w = (const float*)d_in[14];
    const float* r_c2b = (const float*)d_in[15];
    const float* dw1 = (const float*)d_in[16];
    const float* db1 = (const float*)d_in[17];
    const float* dw2 = (const float*)d_in[18];
    const float* db2 = (const float*)d_in[19];
    const float* rw1 = (const float*)d_in[20];
    const float* rb1 = (const float*)d_in[21];
    const float* rw2 = (const float*)d_in[22];
    const float* rb2 = (const float*)d_in[23];
    const float* d_bias = (const float*)d_in[24];
    const float* r_bias = (const float*)d_in[25];
    const int* sidxs  = (const int*)d_in[26];
    const int* nnidxs = (const int*)d_in[27];

    float* out   = (float*)d_out;
    float* d1buf = out;                                 // [B,C,HO,WO]
    float* r1buf = out + (size_t)BB*CC*HWO;

    float* ws = (float*)d_ws;
    size_t off = 0;
    float* d0    = ws + off; off += (size_t)BB*CC*HWO;
    float* r0    = ws + off; off += (size_t)BB*CC*HWO;
    float* aggD  = ws + off; off += (size_t)BB*NS*CC;
    float* aggR  = ws + off; off += (size_t)BB*NS*CC;
    float* dsamp = ws + off; off += (size_t)BB*NS*CC;
    float* rsamp = ws + off; off += (size_t)BB*NS*CC;
    int*   win   = (int*)(ws + off);                    // B*HWO ints

    dim3 cgrid(WOUT/TW, HO/TH, BB);   // 19 x 44 x 2, exact

    conv_s2_dual_tiled<<<cgrid, 256, 0, stream>>>(d_feat, d_c0w, d_c0b, d_c1w, d_c1b, d0, d1buf);
    conv_s2_dual_tiled<<<cgrid, 256, 0, stream>>>(r_feat, r_c0w, r_c0b, r_c1w, r_c1b, r0, r1buf);

    hipMemsetAsync(win, 0xFF, (size_t)BB*HWO*sizeof(int), stream);
    win_kernel<<<(BB*NS + 255)/256, 256, 0, stream>>>(sidxs, win);

    samp_gather<<<dim3(NS, BB), 64, 0, stream>>>(d0, r0, sidxs, dsamp, rsamp);

    attn_kernel<<<dim3(NS, BB), 64, 0, stream>>>(dsamp, rsamp, spoints, nnidxs,
        dw1, db1, dw2, db2, rw1, rb1, rw2, rb2, d_bias, r_bias, aggD, aggR);

    int nelem = BB*CC*HWO;
    blend_kernel<<<(nelem + 255)/256, 256, 0, stream>>>(d0, masks, win, aggD);
    blend_kernel<<<(nelem + 255)/256, 256, 0, stream>>>(r0, masks, win, aggR);

    conv_s1_tiled<<<cgrid, 256, 0, stream>>>(d0, d_c2w, d_c2b, d1buf);
    conv_s1_tiled<<<cgrid, 256, 0, stream>>>(r0, r_c2w, r_c2b, r1buf);
}